// Round 5
// baseline (648.733 us; speedup 1.0000x reference)
//
#include <hip/hip_runtime.h>

// DistanceNetwork: out[b,n] = <support[n,b,:], targets[b,:]> * rsqrt(max(||support[n,b,:]||^2, EPS))
// support_set: [N=512, B=256, D=1024] f32 (512 MiB, streamed once -> nontemporal),
// targets: [B=256, D=1024] f32 (1 MiB, reused N times -> cached path),
// out: [B, N] f32.
// Memory-bound: floor = 537 MB / 6.4 TB/s (measured achievable) ~ 84 us.
// This rev: 2 rows per wave-iteration -> 16 loads in flight, half the
// reduce-stall points per byte streamed.

#define N_SUP 512
#define B_DIM 256
#define D_DIM 1024
#define EPS_CLIP 1e-10f

typedef float f32x4 __attribute__((ext_vector_type(4)));

__global__ __launch_bounds__(256) void distnet_kernel(
    const float* __restrict__ support,
    const float* __restrict__ targets,
    float* __restrict__ out)
{
    const int lane = threadIdx.x & 63;
    const int wave = threadIdx.x >> 6;
    const int waves_per_grid = gridDim.x * 4;
    const int total_pairs = (N_SUP * B_DIM) / 2;   // rows processed in adjacent pairs

    for (int pr = blockIdx.x * 4 + wave; pr < total_pairs; pr += waves_per_grid) {
        const int row0 = pr * 2;                    // even row: b0 even, b1 = b0+1, same n
        const int n  = row0 >> 8;
        const int b0 = row0 & (B_DIM - 1);

        const f32x4* sp0 = reinterpret_cast<const f32x4*>(support + (size_t)row0 * D_DIM);
        const f32x4* sp1 = sp0 + (D_DIM / 4);
        const f32x4* tp0 = reinterpret_cast<const f32x4*>(targets + (size_t)b0 * D_DIM);
        const f32x4* tp1 = tp0 + (D_DIM / 4);

        // 16 loads issued back-to-back (8 NT support, 8 cached targets)
        f32x4 a0 = __builtin_nontemporal_load(sp0 + 0 * 64 + lane);
        f32x4 a1 = __builtin_nontemporal_load(sp0 + 1 * 64 + lane);
        f32x4 a2 = __builtin_nontemporal_load(sp0 + 2 * 64 + lane);
        f32x4 a3 = __builtin_nontemporal_load(sp0 + 3 * 64 + lane);
        f32x4 c0 = __builtin_nontemporal_load(sp1 + 0 * 64 + lane);
        f32x4 c1 = __builtin_nontemporal_load(sp1 + 1 * 64 + lane);
        f32x4 c2 = __builtin_nontemporal_load(sp1 + 2 * 64 + lane);
        f32x4 c3 = __builtin_nontemporal_load(sp1 + 3 * 64 + lane);
        f32x4 t0 = tp0[0 * 64 + lane];
        f32x4 t1 = tp0[1 * 64 + lane];
        f32x4 t2 = tp0[2 * 64 + lane];
        f32x4 t3 = tp0[3 * 64 + lane];
        f32x4 u0 = tp1[0 * 64 + lane];
        f32x4 u1 = tp1[1 * 64 + lane];
        f32x4 u2 = tp1[2 * 64 + lane];
        f32x4 u3 = tp1[3 * 64 + lane];

        float dot0 = 0.0f, ss0 = 0.0f, dot1 = 0.0f, ss1 = 0.0f;
        #pragma unroll
        for (int j = 0; j < 4; ++j) {
            dot0 = fmaf(a0[j], t0[j], dot0);  ss0 = fmaf(a0[j], a0[j], ss0);
            dot1 = fmaf(c0[j], u0[j], dot1);  ss1 = fmaf(c0[j], c0[j], ss1);
        }
        #pragma unroll
        for (int j = 0; j < 4; ++j) {
            dot0 = fmaf(a1[j], t1[j], dot0);  ss0 = fmaf(a1[j], a1[j], ss0);
            dot1 = fmaf(c1[j], u1[j], dot1);  ss1 = fmaf(c1[j], c1[j], ss1);
        }
        #pragma unroll
        for (int j = 0; j < 4; ++j) {
            dot0 = fmaf(a2[j], t2[j], dot0);  ss0 = fmaf(a2[j], a2[j], ss0);
            dot1 = fmaf(c2[j], u2[j], dot1);  ss1 = fmaf(c2[j], c2[j], ss1);
        }
        #pragma unroll
        for (int j = 0; j < 4; ++j) {
            dot0 = fmaf(a3[j], t3[j], dot0);  ss0 = fmaf(a3[j], a3[j], ss0);
            dot1 = fmaf(c3[j], u3[j], dot1);  ss1 = fmaf(c3[j], c3[j], ss1);
        }

        // 64-lane butterfly reduction of all four accumulators
        #pragma unroll
        for (int off = 32; off >= 1; off >>= 1) {
            dot0 += __shfl_xor(dot0, off, 64);
            ss0  += __shfl_xor(ss0,  off, 64);
            dot1 += __shfl_xor(dot1, off, 64);
            ss1  += __shfl_xor(ss1,  off, 64);
        }

        if (lane == 0) {
            out[(size_t)b0 * N_SUP + n]       = dot0 * (1.0f / sqrtf(fmaxf(ss0, EPS_CLIP)));
            out[(size_t)(b0 + 1) * N_SUP + n] = dot1 * (1.0f / sqrtf(fmaxf(ss1, EPS_CLIP)));
        }
    }
}

extern "C" void kernel_launch(void* const* d_in, const int* in_sizes, int n_in,
                              void* d_out, int out_size, void* d_ws, size_t ws_size,
                              hipStream_t stream) {
    const float* support = (const float*)d_in[0];
    const float* targets = (const float*)d_in[1];
    float* out = (float*)d_out;

    // 2048 blocks x 256 threads = 8192 waves; 65536 row-pairs -> 8 pairs/wave.
    distnet_kernel<<<2048, 256, 0, stream>>>(support, targets, out);
}